// Round 3
// baseline (49.504 us; speedup 1.0000x reference)
//
#include <hip/hip_runtime.h>
#include <hip/hip_bf16.h>
#include <float.h>

#define B 16
#define H 32
#define HKV 8
#define G 4
#define D 128
#define LMAX 2048
#define SCALE 0.08838834764831844f  // 1/sqrt(128)

// Kernel 1: per (b, kv-head, split) flash-decode partial.
// part_o : [B][HKV][NSPLIT][G][D]  unnormalized sum of p*V (written only if split non-empty)
// part_ml: [B][HKV][NSPLIT][G][2]  (m, sum_exp)  (always written)
template <int NSPLIT>
__global__ __launch_bounds__(256) void attn_partial(
    const float* __restrict__ q,
    const float* __restrict__ kin,
    const float* __restrict__ vin,
    const float* __restrict__ kc,
    const float* __restrict__ vc,
    const int*  __restrict__ slot_mapping,
    const int*  __restrict__ active_slots,
    const int*  __restrict__ context_lens,
    float* __restrict__ part_o,
    float* __restrict__ part_ml)
{
    constexpr int CHUNK = LMAX / NSPLIT;
    const int tid = threadIdx.x;
    int idx = blockIdx.x;
    const int split = idx % NSPLIT; idx /= NSPLIT;
    const int h = idx % HKV;
    const int b = idx / HKV;

    const int ctx   = context_lens[b];
    const int start = split * CHUNK;
    int nvalid = ctx - start;
    if (nvalid > CHUNK) nvalid = CHUNK;

    const size_t pbase = ((size_t)(b * HKV + h) * NSPLIT + split) * G;

    if (nvalid <= 0) {
        // empty split: l=0 marks it; reduce kernel then skips part_o (left poisoned)
        if (tid < G * 2) part_ml[pbase * 2 + tid] = (tid & 1) ? 0.f : -FLT_MAX;
        return;
    }

    __shared__ float sc[G][CHUNK];          // scores, then p
    __shared__ const float* kp[CHUNK];      // resolved K row pointers
    __shared__ const float* vp[CHUNK];      // resolved V row pointers
    __shared__ float red[8][G][D];          // PV 8-group combine buffer
    __shared__ int   sm[16];

    if (tid < 16) sm[tid] = slot_mapping[tid];
    __syncthreads();

    // ---- Phase 0: resolve slot -> row pointers (coalesced, off the load chain)
    for (int li = tid; li < nvalid; li += 256) {
        const int s = active_slots[b * LMAX + start + li];
        int ov = -1;
#pragma unroll
        for (int j = 0; j < 16; ++j)
            if (sm[j] == s) ov = j;
        if (ov >= 0) {
            kp[li] = kin + ((size_t)ov * HKV + h) * D;
            vp[li] = vin + ((size_t)ov * HKV + h) * D;
        } else {
            kp[li] = kc + ((size_t)s * HKV + h) * D;
            vp[li] = vc + ((size_t)s * HKV + h) * D;
        }
    }
    __syncthreads();

    // ---- Phase 1: QK^T. 32 groups x 8 lanes; each group one slot per iter.
    const int grp   = tid >> 3;   // 0..31
    const int lane8 = tid & 7;    // 0..7

    float4 qv[G][4];
#pragma unroll
    for (int g = 0; g < G; ++g) {
        const float* qp = q + ((size_t)(b * H + h * G + g)) * D;
#pragma unroll
        for (int i = 0; i < 4; ++i) {
            float4 t = *(const float4*)(qp + i * 32 + lane8 * 4);
            qv[g][i] = make_float4(t.x * SCALE, t.y * SCALE, t.z * SCALE, t.w * SCALE);
        }
    }

    for (int li = grp; li < nvalid; li += 32) {
        const float* kb = kp[li];
        float pd0 = 0.f, pd1 = 0.f, pd2 = 0.f, pd3 = 0.f;
#pragma unroll
        for (int i = 0; i < 4; ++i) {
            float4 kv = *(const float4*)(kb + i * 32 + lane8 * 4);
            pd0 += kv.x * qv[0][i].x + kv.y * qv[0][i].y + kv.z * qv[0][i].z + kv.w * qv[0][i].w;
            pd1 += kv.x * qv[1][i].x + kv.y * qv[1][i].y + kv.z * qv[1][i].z + kv.w * qv[1][i].w;
            pd2 += kv.x * qv[2][i].x + kv.y * qv[2][i].y + kv.z * qv[2][i].z + kv.w * qv[2][i].w;
            pd3 += kv.x * qv[3][i].x + kv.y * qv[3][i].y + kv.z * qv[3][i].z + kv.w * qv[3][i].w;
        }
#pragma unroll
        for (int msk = 1; msk < 8; msk <<= 1) {
            pd0 += __shfl_xor(pd0, msk, 8);
            pd1 += __shfl_xor(pd1, msk, 8);
            pd2 += __shfl_xor(pd2, msk, 8);
            pd3 += __shfl_xor(pd3, msk, 8);
        }
        if (lane8 == 0) {
            sc[0][li] = pd0; sc[1][li] = pd1; sc[2][li] = pd2; sc[3][li] = pd3;
        }
    }
    __syncthreads();

    // ---- Phase 2: softmax. Wave w handles head g=w.
    {
        const int g    = tid >> 6;
        const int lane = tid & 63;
        float m = -FLT_MAX;
        for (int i = lane; i < nvalid; i += 64) m = fmaxf(m, sc[g][i]);
#pragma unroll
        for (int msk = 1; msk < 64; msk <<= 1) m = fmaxf(m, __shfl_xor(m, msk, 64));
        float sum = 0.f;
        for (int i = lane; i < nvalid; i += 64) {
            float p = __expf(sc[g][i] - m);
            sc[g][i] = p;
            sum += p;
        }
#pragma unroll
        for (int msk = 1; msk < 64; msk <<= 1) sum += __shfl_xor(sum, msk, 64);
        if (lane == 0) {
            part_ml[(pbase + g) * 2 + 0] = m;
            part_ml[(pbase + g) * 2 + 1] = sum;
        }
    }
    __syncthreads();

    // ---- Phase 3: PV. 8 slot-groups x 32 d-threads, float4 V loads, all 4 heads.
    {
        const int grp8  = tid >> 5;       // 0..7
        const int dlane = tid & 31;       // 0..31
        const int db    = dlane * 4;
        float4 a0 = {0,0,0,0}, a1 = {0,0,0,0}, a2 = {0,0,0,0}, a3 = {0,0,0,0};
#pragma unroll 4
        for (int i = grp8; i < nvalid; i += 8) {
            const float4 vv = *(const float4*)(vp[i] + db);
            const float p0 = sc[0][i], p1 = sc[1][i], p2 = sc[2][i], p3 = sc[3][i];
            a0.x += p0 * vv.x; a0.y += p0 * vv.y; a0.z += p0 * vv.z; a0.w += p0 * vv.w;
            a1.x += p1 * vv.x; a1.y += p1 * vv.y; a1.z += p1 * vv.z; a1.w += p1 * vv.w;
            a2.x += p2 * vv.x; a2.y += p2 * vv.y; a2.z += p2 * vv.z; a2.w += p2 * vv.w;
            a3.x += p3 * vv.x; a3.y += p3 * vv.y; a3.z += p3 * vv.z; a3.w += p3 * vv.w;
        }
        *(float4*)(&red[grp8][0][db]) = a0;
        *(float4*)(&red[grp8][1][db]) = a1;
        *(float4*)(&red[grp8][2][db]) = a2;
        *(float4*)(&red[grp8][3][db]) = a3;
    }
    __syncthreads();

    // ---- Phase 4: combine the 8 PV groups, write part_o. 512 outputs, 2/thread.
    {
#pragma unroll
        for (int k2 = 0; k2 < 2; ++k2) {
            const int oidx = tid * 2 + k2;       // [G][D]
            const int g = oidx >> 7;
            const int d = oidx & 127;
            float s = 0.f;
#pragma unroll
            for (int r = 0; r < 8; ++r) s += red[r][g][d];
            part_o[(pbase + g) * D + d] = s;
        }
    }
}

// Kernel 2: merge nsplit partials per (b, head) with log-sum-exp combine.
__global__ __launch_bounds__(128) void attn_reduce(
    const float* __restrict__ part_o,
    const float* __restrict__ part_ml,
    float* __restrict__ out,
    int nsplit)
{
    int idx = blockIdx.x;                 // [B][HKV][G]
    const int g = idx & 3;
    const int h = (idx >> 2) & 7;
    const int b = idx >> 5;
    const int d = threadIdx.x;

    const size_t base = (size_t)(b * HKV + h) * nsplit;

    float M = -FLT_MAX;
    for (int s = 0; s < nsplit; ++s) {
        const float l = part_ml[((base + s) * G + g) * 2 + 1];
        if (l > 0.f) M = fmaxf(M, part_ml[((base + s) * G + g) * 2 + 0]);
    }
    float L = 0.f, acc = 0.f;
    for (int s = 0; s < nsplit; ++s) {
        const float l = part_ml[((base + s) * G + g) * 2 + 1];
        if (l > 0.f) {
            const float e = __expf(part_ml[((base + s) * G + g) * 2 + 0] - M);
            L += l * e;
            acc += e * part_o[((base + s) * G + g) * D + d];
        }
    }
    out[((size_t)(b * H) + h * G + g) * D + d] = acc / (L > 0.f ? L : 1.f);
}

extern "C" void kernel_launch(void* const* d_in, const int* in_sizes, int n_in,
                              void* d_out, int out_size, void* d_ws, size_t ws_size,
                              hipStream_t stream) {
    const float* q  = (const float*)d_in[0];
    const float* k  = (const float*)d_in[1];
    const float* v  = (const float*)d_in[2];
    const float* kc = (const float*)d_in[3];
    const float* vc = (const float*)d_in[4];
    const int* slot_mapping = (const int*)d_in[5];
    const int* active_slots = (const int*)d_in[6];
    const int* context_lens = (const int*)d_in[7];
    float* out = (float*)d_out;

    const size_t perSplit = (size_t)B * HKV * (G * D + G * 2) * sizeof(float);
    int nsplit = 8;
    if (ws_size >= 32 * perSplit)      nsplit = 32;
    else if (ws_size >= 16 * perSplit) nsplit = 16;

    float* part_o  = (float*)d_ws;
    float* part_ml = part_o + (size_t)B * HKV * nsplit * G * D;

    if (nsplit == 32) {
        attn_partial<32><<<B * HKV * 32, 256, 0, stream>>>(
            q, k, v, kc, vc, slot_mapping, active_slots, context_lens, part_o, part_ml);
    } else if (nsplit == 16) {
        attn_partial<16><<<B * HKV * 16, 256, 0, stream>>>(
            q, k, v, kc, vc, slot_mapping, active_slots, context_lens, part_o, part_ml);
    } else {
        attn_partial<8><<<B * HKV * 8, 256, 0, stream>>>(
            q, k, v, kc, vc, slot_mapping, active_slots, context_lens, part_o, part_ml);
    }
    attn_reduce<<<B * HKV * G, 128, 0, stream>>>(part_o, part_ml, out, nsplit);
}